// Round 6
// baseline (137.527 us; speedup 1.0000x reference)
//
#include <hip/hip_runtime.h>

#define NB   8
#define ND   64
#define NP   1024
#define KDIM 128
#define HID  256
#define OUTD 256
#define CSC  2.885390081777927f   // 2*log2(e)

// E-trick: E = exp2(CSC*proj) = e^{2*proj};
// sigma = 1/(1 + Ed*Ep) = rcp(fma(Ed,Ep,1));  tanh(xd+xp) = 1 - 2*sigma.

// K1: projections + exp2. 16 rows x 128 h-cols; waves 0-1 do W1, waves 2-3 do W2.
// blocks [0,1024): protein side; [1024,1088): drug side.
__global__ __launch_bounds__(256) void k_proj(
    const float* __restrict__ Xd, const float* __restrict__ Xp,
    const float* __restrict__ Wd, const float* __restrict__ Wa,
    const float* __restrict__ Wp, const float* __restrict__ Wb,
    float* __restrict__ Ehd, float* __restrict__ Efd,
    float* __restrict__ Ehp, float* __restrict__ Efp) {
    int blk = blockIdx.x, t = threadIdx.x;
    const float *X, *W1, *W2;
    float *O1, *O2;
    int row0, half;
    if (blk < 1024) {
        int rb = blk >> 1; half = blk & 1;
        int b = rb >> 6, jt = rb & 63;
        row0 = b * NP + jt * 16; X = Xp; W1 = Wp; W2 = Wb; O1 = Ehp; O2 = Efp;
    } else {
        int r = blk - 1024;
        int rb = r >> 1; half = r & 1;
        int b = rb >> 2, it = rb & 3;
        row0 = b * ND + it * 16; X = Xd; W1 = Wd; W2 = Wa; O1 = Ehd; O2 = Efd;
    }
    int os = t >> 7, hl = t & 127;      // os wave-uniform: waves 0-1 vs 2-3
    int h = (half << 7) + hl;
    const float* W = os ? W2 : W1;
    float* O = os ? O2 : O1;
    __shared__ float4 xs[512];          // 16 rows x 128 k = 8 KB
    xs[t]       = ((const float4*)(X + row0 * KDIM))[t];
    xs[t + 256] = ((const float4*)(X + row0 * KDIM))[t + 256];
    __syncthreads();
    float acc[16];
#pragma unroll
    for (int r = 0; r < 16; ++r) acc[r] = 0.f;
#pragma unroll 2
    for (int k4 = 0; k4 < 32; ++k4) {
        int k = k4 << 2;
        float w0 = W[(k + 0) * HID + h], w1 = W[(k + 1) * HID + h];
        float w2 = W[(k + 2) * HID + h], w3 = W[(k + 3) * HID + h];
#pragma unroll
        for (int r = 0; r < 16; ++r) {
            float4 x = xs[(r << 5) + k4];   // LDS b128 broadcast
            acc[r] = fmaf(x.x, w0, acc[r]);
            acc[r] = fmaf(x.y, w1, acc[r]);
            acc[r] = fmaf(x.z, w2, acc[r]);
            acc[r] = fmaf(x.w, w3, acc[r]);
        }
    }
#pragma unroll
    for (int r = 0; r < 16; ++r)
        O[(row0 + r) * HID + h] = __builtin_amdgcn_exp2f(acc[r] * CSC);
}

// K2: shifted scores S[b,i,j] = -2 * sum_h w_h * rcp(1 + Ehd*Ehp).
// No LDS at all. Tile 8 i x 32 j, one (i,j) per thread. grid = 2048.
// Ehd: 2 distinct rows per wave (L1); Ehp: per-lane row stream (64B line
// serves 4 iters); wsc: wave-uniform -> scalar loads.
__global__ __launch_bounds__(256) void k_scores(
    const float* __restrict__ Ehd, const float* __restrict__ Ehp,
    const float* __restrict__ wsc, float* __restrict__ S) {
    int blk = blockIdx.x;
    int b = blk >> 8, r = blk & 255, ih = r >> 5, jt = r & 31;
    int t = threadIdx.x;
    int jg = t & 31, il = t >> 5;
    int i = ih * 8 + il, j = jt * 32 + jg;
    const float4* hv4 = (const float4*)(Ehd + ((b * ND + i) << 8));
    const float4* pv4 = (const float4*)(Ehp + ((b * NP + j) << 8));
    const float4* w4  = (const float4*)wsc;
    float acc = 0.f;
#pragma unroll 4
    for (int h4 = 0; h4 < 64; ++h4) {
        float4 hv = hv4[h4];
        float4 pv = pv4[h4];
        float4 wv = w4[h4];
        acc = fmaf(wv.x, __builtin_amdgcn_rcpf(fmaf(hv.x, pv.x, 1.f)), acc);
        acc = fmaf(wv.y, __builtin_amdgcn_rcpf(fmaf(hv.y, pv.y, 1.f)), acc);
        acc = fmaf(wv.z, __builtin_amdgcn_rcpf(fmaf(hv.z, pv.z, 1.f)), acc);
        acc = fmaf(wv.w, __builtin_amdgcn_rcpf(fmaf(hv.w, pv.w, 1.f)), acc);
    }
    S[((b * ND + i) << 10) + j] = -2.f * acc;
}

// K3: softmax over j per (b,i) row, in place; writes A2 = -2*A.
// No max pass: |S| <= 2*sum|w| <= 32, exp2 arg <= ~46 -> fp32-safe.
__global__ __launch_bounds__(256) void k_softmax(float* __restrict__ S) {
    int row = blockIdx.x;
    int t = threadIdx.x;
    float* Srow = S + (row << 10);
    float4 v = ((float4*)Srow)[t];
    const float L2E = 1.4426950408889634f;
    v.x = __builtin_amdgcn_exp2f(v.x * L2E);
    v.y = __builtin_amdgcn_exp2f(v.y * L2E);
    v.z = __builtin_amdgcn_exp2f(v.z * L2E);
    v.w = __builtin_amdgcn_exp2f(v.w * L2E);
    float s4 = (v.x + v.y) + (v.z + v.w);
#pragma unroll
    for (int off = 32; off > 0; off >>= 1) s4 += __shfl_xor(s4, off, 64);
    __shared__ float wsum[4];
    if ((t & 63) == 0) wsum[t >> 6] = s4;
    __syncthreads();
    float tot = (wsum[0] + wsum[1]) + (wsum[2] + wsum[3]);
    float sneg = -2.0f * __builtin_amdgcn_rcpf(tot);   // A2 = -2*A
    v.x *= sneg; v.y *= sneg; v.z *= sneg; v.w *= sneg;
    ((float4*)Srow)[t] = v;
}

// K4: partial[blk][o] = sum_{i in 32, j in 16} A2 * rcp(1 + Efd*Efp).
// (X_int = 64 + sum of all partials, since sum_j A = 1 per i.)
// Efd from L2 (coalesced 1 KB/wave loads); LDS = 6 KB. grid = 1024.
__global__ __launch_bounds__(256) void k_facc(
    const float* __restrict__ Efd, const float* __restrict__ Efp,
    const float* __restrict__ A2, float* __restrict__ part) {
    int blk = blockIdx.x;
    int b = blk >> 7, rr = blk & 127, ih = rr >> 6, jt = rr & 63;
    int i0 = ih * 32, j0 = jt * 16;
    int t = threadIdx.x;
    __shared__ float4 as4[32 * 4];    // 2 KB  (A2 tile [32 i][16 j])
    __shared__ float4 red[256];       // 4 KB
    if (t < 128) {
        int ii = t >> 2, jq = t & 3;
        as4[t] = ((const float4*)A2)[((b * ND + i0 + ii) << 8) + (j0 >> 2) + jq];
    }
    __syncthreads();

    int o4 = t & 63, jq = t >> 6;
    const float4* fdg = (const float4*)(Efd + ((b * ND + i0) << 8));
    const float4* fpg = (const float4*)(Efp + ((b * NP + j0 + (jq << 2)) << 8));
    float4 fv0 = fpg[o4], fv1 = fpg[64 + o4], fv2 = fpg[128 + o4], fv3 = fpg[192 + o4];
    float4 acc = {0.f, 0.f, 0.f, 0.f};
    for (int i = 0; i < 32; ++i) {
        float4 dv = fdg[(i << 6) + o4];   // global, coalesced, L2-hit
        float4 a  = as4[(i << 2) + jq];
        acc.x = fmaf(a.x, __builtin_amdgcn_rcpf(fmaf(dv.x, fv0.x, 1.f)), acc.x);
        acc.y = fmaf(a.x, __builtin_amdgcn_rcpf(fmaf(dv.y, fv0.y, 1.f)), acc.y);
        acc.z = fmaf(a.x, __builtin_amdgcn_rcpf(fmaf(dv.z, fv0.z, 1.f)), acc.z);
        acc.w = fmaf(a.x, __builtin_amdgcn_rcpf(fmaf(dv.w, fv0.w, 1.f)), acc.w);
        acc.x = fmaf(a.y, __builtin_amdgcn_rcpf(fmaf(dv.x, fv1.x, 1.f)), acc.x);
        acc.y = fmaf(a.y, __builtin_amdgcn_rcpf(fmaf(dv.y, fv1.y, 1.f)), acc.y);
        acc.z = fmaf(a.y, __builtin_amdgcn_rcpf(fmaf(dv.z, fv1.z, 1.f)), acc.z);
        acc.w = fmaf(a.y, __builtin_amdgcn_rcpf(fmaf(dv.w, fv1.w, 1.f)), acc.w);
        acc.x = fmaf(a.z, __builtin_amdgcn_rcpf(fmaf(dv.x, fv2.x, 1.f)), acc.x);
        acc.y = fmaf(a.z, __builtin_amdgcn_rcpf(fmaf(dv.y, fv2.y, 1.f)), acc.y);
        acc.z = fmaf(a.z, __builtin_amdgcn_rcpf(fmaf(dv.z, fv2.z, 1.f)), acc.z);
        acc.w = fmaf(a.z, __builtin_amdgcn_rcpf(fmaf(dv.w, fv2.w, 1.f)), acc.w);
        acc.x = fmaf(a.w, __builtin_amdgcn_rcpf(fmaf(dv.x, fv3.x, 1.f)), acc.x);
        acc.y = fmaf(a.w, __builtin_amdgcn_rcpf(fmaf(dv.y, fv3.y, 1.f)), acc.y);
        acc.z = fmaf(a.w, __builtin_amdgcn_rcpf(fmaf(dv.z, fv3.z, 1.f)), acc.z);
        acc.w = fmaf(a.w, __builtin_amdgcn_rcpf(fmaf(dv.w, fv3.w, 1.f)), acc.w);
    }
    red[t] = acc; __syncthreads();
    if (t < 64) {
        float4 r0 = red[t], r1 = red[64 + t], r2 = red[128 + t], r3 = red[192 + t];
        float4 s;
        s.x = (r0.x + r1.x) + (r2.x + r3.x);
        s.y = (r0.y + r1.y) + (r2.y + r3.y);
        s.z = (r0.z + r1.z) + (r2.z + r3.z);
        s.w = (r0.w + r1.w) + (r2.w + r3.w);
        ((float4*)part)[(blk << 6) + t] = s;
    }
}

// K5: out[b][o] = 64 + sum over 128 partials. Deterministic.
__global__ __launch_bounds__(256) void k_reduce(
    const float* __restrict__ part, float* __restrict__ out) {
    int b = blockIdx.x;
    int t = threadIdx.x;
    float s = 64.0f;   // sum_i sum_j A_ij * 1
    for (int q = 0; q < 128; ++q)
        s += part[((b * 128 + q) << 8) + t];
    out[(b << 8) + t] = s;
}

extern "C" void kernel_launch(void* const* d_in, const int* in_sizes, int n_in,
                              void* d_out, int out_size, void* d_ws, size_t ws_size,
                              hipStream_t stream) {
    const float* Xd  = (const float*)d_in[0];
    const float* Xp  = (const float*)d_in[1];
    const float* Wd  = (const float*)d_in[2];
    const float* Wp  = (const float*)d_in[3];
    const float* Wa  = (const float*)d_in[4];
    const float* Wb  = (const float*)d_in[5];
    const float* wsc = (const float*)d_in[6];
    float* out = (float*)d_out;

    float* ws = (float*)d_ws;
    float* Ehd  = ws;                       // 131072
    float* Efd  = Ehd + NB * ND * HID;      // 131072
    float* Ehp  = Efd + NB * ND * OUTD;     // 2097152
    float* Efp  = Ehp + NB * NP * HID;      // 2097152
    float* S    = Efp + NB * NP * OUTD;     // 524288
    float* part = Ehp;                      // overlay: Ehp dead after k_scores

    k_proj   <<<1088, 256, 0, stream>>>(Xd, Xp, Wd, Wa, Wp, Wb, Ehd, Efd, Ehp, Efp);
    k_scores <<<2048, 256, 0, stream>>>(Ehd, Ehp, wsc, S);
    k_softmax<<<NB * ND, 256, 0, stream>>>(S);
    k_facc   <<<NB * 128, 256, 0, stream>>>(Efd, Efp, S, part);
    k_reduce <<<NB, 256, 0, stream>>>(part, out);
}

// Round 7
// 88.410 us; speedup vs baseline: 1.5556x; 1.5556x over previous
//
#include <hip/hip_runtime.h>

#define NB   8
#define ND   64
#define NP   1024
#define KDIM 128
#define HID  256
#define OUTD 256
#define CSC  2.885390081777927f   // 2*log2(e)

// E-trick: E = exp2(CSC*proj) = e^{2*proj};
// sigma = 1/(1 + Ed*Ep) = rcp(fma(Ed,Ep,1));  tanh(xd+xp) = 1 - 2*sigma.
// Ehp is stored TRANSPOSED: EhpT[b][h][j]  -> coalesced j-reads in k_scores.

// K1: projections + exp2. 16 rows x 128 h-cols; waves 0-1 do W1, waves 2-3 do W2.
// blocks [0,1024): protein side; [1024,1088): drug side.
__global__ __launch_bounds__(256) void k_proj(
    const float* __restrict__ Xd, const float* __restrict__ Xp,
    const float* __restrict__ Wd, const float* __restrict__ Wa,
    const float* __restrict__ Wp, const float* __restrict__ Wb,
    float* __restrict__ Ehd, float* __restrict__ Efd,
    float* __restrict__ EhpT, float* __restrict__ Efp) {
    int blk = blockIdx.x, t = threadIdx.x;
    const float *X, *W1, *W2;
    int row0, half, prot, pb = 0, pj0 = 0;
    if (blk < 1024) {
        int rb = blk >> 1; half = blk & 1;
        int b = rb >> 6, jt = rb & 63;
        row0 = b * NP + jt * 16; X = Xp; W1 = Wp; W2 = Wb;
        prot = 1; pb = b; pj0 = jt * 16;
    } else {
        int r = blk - 1024;
        int rb = r >> 1; half = r & 1;
        int b = rb >> 2, it = rb & 3;
        row0 = b * ND + it * 16; X = Xd; W1 = Wd; W2 = Wa;
        prot = 0;
    }
    int os = t >> 7, hl = t & 127;      // os wave-uniform: waves 0-1 vs 2-3
    int h = (half << 7) + hl;
    const float* W = os ? W2 : W1;
    __shared__ float4 xs[512];          // 16 rows x 128 k = 8 KB
    xs[t]       = ((const float4*)(X + row0 * KDIM))[t];
    xs[t + 256] = ((const float4*)(X + row0 * KDIM))[t + 256];
    __syncthreads();
    float acc[16];
#pragma unroll
    for (int r = 0; r < 16; ++r) acc[r] = 0.f;
#pragma unroll 2
    for (int k4 = 0; k4 < 32; ++k4) {
        int k = k4 << 2;
        float w0 = W[(k + 0) * HID + h], w1 = W[(k + 1) * HID + h];
        float w2 = W[(k + 2) * HID + h], w3 = W[(k + 3) * HID + h];
#pragma unroll
        for (int r = 0; r < 16; ++r) {
            float4 x = xs[(r << 5) + k4];   // LDS b128 broadcast
            acc[r] = fmaf(x.x, w0, acc[r]);
            acc[r] = fmaf(x.y, w1, acc[r]);
            acc[r] = fmaf(x.z, w2, acc[r]);
            acc[r] = fmaf(x.w, w3, acc[r]);
        }
    }
    if (prot && os == 0) {
        // transposed store: EhpT[b][h][j0..j0+15] = one 64B line, 4x float4
        float4* dst = (float4*)(EhpT + ((size_t)((pb << 8) + h)) * NP + pj0);
#pragma unroll
        for (int q = 0; q < 4; ++q) {
            float4 v;
            v.x = __builtin_amdgcn_exp2f(acc[4 * q + 0] * CSC);
            v.y = __builtin_amdgcn_exp2f(acc[4 * q + 1] * CSC);
            v.z = __builtin_amdgcn_exp2f(acc[4 * q + 2] * CSC);
            v.w = __builtin_amdgcn_exp2f(acc[4 * q + 3] * CSC);
            dst[q] = v;
        }
    } else {
        float* O = prot ? Efp : (os ? Efd : Ehd);
#pragma unroll
        for (int r = 0; r < 16; ++r)
            O[(row0 + r) * HID + h] = __builtin_amdgcn_exp2f(acc[r] * CSC);
    }
}

// K2: shifted scores S[b,i,j] = -2 * sum_h w_h * rcp(1 + Ehd*EhpT).
// No LDS, no barrier. Block = 8 i x 64 j; thread: jg = t&63 (coalesced j),
// iq = t>>6 wave-uniform -> Ehd/w loads are scalar. grid = 8*8*16 = 1024.
__global__ __launch_bounds__(256) void k_scores(
    const float* __restrict__ Ehd, const float* __restrict__ EhpT,
    const float* __restrict__ wsc, float* __restrict__ S) {
    int blk = blockIdx.x;
    int b = blk >> 7, r = blk & 127, it = r >> 4, jt = r & 15;
    int i0 = it * 8, j0 = jt * 64;
    int t = threadIdx.x;
    int jg = t & 63, iq = t >> 6;
    int i = i0 + iq * 2;
    const float4* h0v4 = (const float4*)(Ehd + ((b * ND + i) << 8));
    const float4* h1v4 = (const float4*)(Ehd + ((b * ND + i + 1) << 8));
    const float4* w4   = (const float4*)wsc;
    const float* pT = EhpT + ((size_t)(b << 8)) * NP + j0 + jg;
    float acc0 = 0.f, acc1 = 0.f;
#pragma unroll 4
    for (int h4 = 0; h4 < 64; ++h4) {
        float4 h0 = h0v4[h4];           // wave-uniform (scalar)
        float4 h1 = h1v4[h4];
        float4 wv = w4[h4];
        float p0 = pT[(h4 * 4 + 0) * NP];   // coalesced 256B
        float p1 = pT[(h4 * 4 + 1) * NP];
        float p2 = pT[(h4 * 4 + 2) * NP];
        float p3 = pT[(h4 * 4 + 3) * NP];
        acc0 = fmaf(wv.x, __builtin_amdgcn_rcpf(fmaf(h0.x, p0, 1.f)), acc0);
        acc0 = fmaf(wv.y, __builtin_amdgcn_rcpf(fmaf(h0.y, p1, 1.f)), acc0);
        acc0 = fmaf(wv.z, __builtin_amdgcn_rcpf(fmaf(h0.z, p2, 1.f)), acc0);
        acc0 = fmaf(wv.w, __builtin_amdgcn_rcpf(fmaf(h0.w, p3, 1.f)), acc0);
        acc1 = fmaf(wv.x, __builtin_amdgcn_rcpf(fmaf(h1.x, p0, 1.f)), acc1);
        acc1 = fmaf(wv.y, __builtin_amdgcn_rcpf(fmaf(h1.y, p1, 1.f)), acc1);
        acc1 = fmaf(wv.z, __builtin_amdgcn_rcpf(fmaf(h1.z, p2, 1.f)), acc1);
        acc1 = fmaf(wv.w, __builtin_amdgcn_rcpf(fmaf(h1.w, p3, 1.f)), acc1);
    }
    int base = ((b * ND + i) << 10) + j0 + jg;
    S[base]        = -2.f * acc0;
    S[base + 1024] = -2.f * acc1;
}

// K3: softmax over j per (b,i) row, in place; writes A2 = -2*A.
// No max pass: |S| <= 2*sum|w| <= 32, exp2 arg <= ~46 -> fp32-safe.
__global__ __launch_bounds__(256) void k_softmax(float* __restrict__ S) {
    int row = blockIdx.x;
    int t = threadIdx.x;
    float* Srow = S + (row << 10);
    float4 v = ((float4*)Srow)[t];
    const float L2E = 1.4426950408889634f;
    v.x = __builtin_amdgcn_exp2f(v.x * L2E);
    v.y = __builtin_amdgcn_exp2f(v.y * L2E);
    v.z = __builtin_amdgcn_exp2f(v.z * L2E);
    v.w = __builtin_amdgcn_exp2f(v.w * L2E);
    float s4 = (v.x + v.y) + (v.z + v.w);
#pragma unroll
    for (int off = 32; off > 0; off >>= 1) s4 += __shfl_xor(s4, off, 64);
    __shared__ float wsum[4];
    if ((t & 63) == 0) wsum[t >> 6] = s4;
    __syncthreads();
    float tot = (wsum[0] + wsum[1]) + (wsum[2] + wsum[3]);
    float sneg = -2.0f * __builtin_amdgcn_rcpf(tot);   // A2 = -2*A
    v.x *= sneg; v.y *= sneg; v.z *= sneg; v.w *= sneg;
    ((float4*)Srow)[t] = v;
}

// K4: partial[blk][o] = sum_{i in 32, j in 16} A2 * rcp(1 + Efd*Efp).
// (X_int = 64 + sum of all partials, since sum_j A = 1 per i.)
// Efd from L2 (coalesced 1 KB/wave loads); LDS = 6 KB. grid = 1024.
__global__ __launch_bounds__(256) void k_facc(
    const float* __restrict__ Efd, const float* __restrict__ Efp,
    const float* __restrict__ A2, float* __restrict__ part) {
    int blk = blockIdx.x;
    int b = blk >> 7, rr = blk & 127, ih = rr >> 6, jt = rr & 63;
    int i0 = ih * 32, j0 = jt * 16;
    int t = threadIdx.x;
    __shared__ float4 as4[32 * 4];    // 2 KB  (A2 tile [32 i][16 j])
    __shared__ float4 red[256];       // 4 KB
    if (t < 128) {
        int ii = t >> 2, jq = t & 3;
        as4[t] = ((const float4*)A2)[((b * ND + i0 + ii) << 8) + (j0 >> 2) + jq];
    }
    __syncthreads();

    int o4 = t & 63, jq = t >> 6;
    const float4* fdg = (const float4*)(Efd + ((b * ND + i0) << 8));
    const float4* fpg = (const float4*)(Efp + ((b * NP + j0 + (jq << 2)) << 8));
    float4 fv0 = fpg[o4], fv1 = fpg[64 + o4], fv2 = fpg[128 + o4], fv3 = fpg[192 + o4];
    float4 acc = {0.f, 0.f, 0.f, 0.f};
    for (int i = 0; i < 32; ++i) {
        float4 dv = fdg[(i << 6) + o4];   // global, coalesced, L2-hit
        float4 a  = as4[(i << 2) + jq];
        acc.x = fmaf(a.x, __builtin_amdgcn_rcpf(fmaf(dv.x, fv0.x, 1.f)), acc.x);
        acc.y = fmaf(a.x, __builtin_amdgcn_rcpf(fmaf(dv.y, fv0.y, 1.f)), acc.y);
        acc.z = fmaf(a.x, __builtin_amdgcn_rcpf(fmaf(dv.z, fv0.z, 1.f)), acc.z);
        acc.w = fmaf(a.x, __builtin_amdgcn_rcpf(fmaf(dv.w, fv0.w, 1.f)), acc.w);
        acc.x = fmaf(a.y, __builtin_amdgcn_rcpf(fmaf(dv.x, fv1.x, 1.f)), acc.x);
        acc.y = fmaf(a.y, __builtin_amdgcn_rcpf(fmaf(dv.y, fv1.y, 1.f)), acc.y);
        acc.z = fmaf(a.y, __builtin_amdgcn_rcpf(fmaf(dv.z, fv1.z, 1.f)), acc.z);
        acc.w = fmaf(a.y, __builtin_amdgcn_rcpf(fmaf(dv.w, fv1.w, 1.f)), acc.w);
        acc.x = fmaf(a.z, __builtin_amdgcn_rcpf(fmaf(dv.x, fv2.x, 1.f)), acc.x);
        acc.y = fmaf(a.z, __builtin_amdgcn_rcpf(fmaf(dv.y, fv2.y, 1.f)), acc.y);
        acc.z = fmaf(a.z, __builtin_amdgcn_rcpf(fmaf(dv.z, fv2.z, 1.f)), acc.z);
        acc.w = fmaf(a.z, __builtin_amdgcn_rcpf(fmaf(dv.w, fv2.w, 1.f)), acc.w);
        acc.x = fmaf(a.w, __builtin_amdgcn_rcpf(fmaf(dv.x, fv3.x, 1.f)), acc.x);
        acc.y = fmaf(a.w, __builtin_amdgcn_rcpf(fmaf(dv.y, fv3.y, 1.f)), acc.y);
        acc.z = fmaf(a.w, __builtin_amdgcn_rcpf(fmaf(dv.z, fv3.z, 1.f)), acc.z);
        acc.w = fmaf(a.w, __builtin_amdgcn_rcpf(fmaf(dv.w, fv3.w, 1.f)), acc.w);
    }
    red[t] = acc; __syncthreads();
    if (t < 64) {
        float4 r0 = red[t], r1 = red[64 + t], r2 = red[128 + t], r3 = red[192 + t];
        float4 s;
        s.x = (r0.x + r1.x) + (r2.x + r3.x);
        s.y = (r0.y + r1.y) + (r2.y + r3.y);
        s.z = (r0.z + r1.z) + (r2.z + r3.z);
        s.w = (r0.w + r1.w) + (r2.w + r3.w);
        ((float4*)part)[(blk << 6) + t] = s;
    }
}

// K5: out[b][o] = 64 + sum over 128 partials. 64 blocks (8b x 8 o-chunks).
__global__ __launch_bounds__(256) void k_reduce(
    const float* __restrict__ part, float* __restrict__ out) {
    int b = blockIdx.x >> 3, oc = blockIdx.x & 7;
    int t = threadIdx.x;
    int o = oc * 32 + (t & 31), q0 = t >> 5;
    float s = 0.f;
#pragma unroll
    for (int k = 0; k < 16; ++k)
        s += part[((b * 128 + q0 + k * 8) << 8) + o];
    __shared__ float red[256];
    red[t] = s; __syncthreads();
    for (int st = 128; st >= 32; st >>= 1) {
        if (t < st) red[t] += red[t + st];
        __syncthreads();
    }
    if (t < 32) out[(b << 8) + oc * 32 + t] = 64.0f + red[t];
}

extern "C" void kernel_launch(void* const* d_in, const int* in_sizes, int n_in,
                              void* d_out, int out_size, void* d_ws, size_t ws_size,
                              hipStream_t stream) {
    const float* Xd  = (const float*)d_in[0];
    const float* Xp  = (const float*)d_in[1];
    const float* Wd  = (const float*)d_in[2];
    const float* Wp  = (const float*)d_in[3];
    const float* Wa  = (const float*)d_in[4];
    const float* Wb  = (const float*)d_in[5];
    const float* wsc = (const float*)d_in[6];
    float* out = (float*)d_out;

    float* ws = (float*)d_ws;
    float* Ehd  = ws;                       // 131072
    float* Efd  = Ehd + NB * ND * HID;      // 131072
    float* EhpT = Efd + NB * ND * OUTD;     // 2097152  (transposed [b][h][j])
    float* Efp  = EhpT + NB * NP * HID;     // 2097152
    float* S    = Efp + NB * NP * OUTD;     // 524288
    float* part = EhpT;                     // overlay: EhpT dead after k_scores

    k_proj   <<<1088, 256, 0, stream>>>(Xd, Xp, Wd, Wa, Wp, Wb, Ehd, Efd, EhpT, Efp);
    k_scores <<<1024, 256, 0, stream>>>(Ehd, EhpT, wsc, S);
    k_softmax<<<NB * ND, 256, 0, stream>>>(S);
    k_facc   <<<NB * 128, 256, 0, stream>>>(Efd, Efp, S, part);
    k_reduce <<<64, 256, 0, stream>>>(part, out);
}